// Round 1
// baseline (692.619 us; speedup 1.0000x reference)
//
#include <hip/hip_runtime.h>
#include <hip/hip_bf16.h>
#include <math.h>

// Problem constants (SparseAttention_46969762349725)
#define HEADS 8
#define IN_C  256
#define MDL   512
#define NB    4        // batch
#define LL    4096     // nodes
#define NE    65536    // edges
#define EDIM  64       // per-head dim = MDL/HEADS
#define TEMP  0.125f   // 1/sqrt(64)

// ---------------- generic fp32 GEMM: C = A[MxK] @ B[KxN] + bias[N] ----------
#define BM 64
#define BN 64
#define BK 16

__global__ __launch_bounds__(256) void gemm_bias(
    const float* __restrict__ A, const float* __restrict__ B,
    const float* __restrict__ bias, float* __restrict__ C,
    int M, int N, int K)
{
    __shared__ float As[BK][BM + 1];
    __shared__ float Bs[BK][BN];

    const int tid = threadIdx.x;           // 256 threads
    const int bm  = blockIdx.y * BM;
    const int bn  = blockIdx.x * BN;
    const int tr  = (tid >> 4) * 4;        // 0..60
    const int tc  = (tid & 15) * 4;        // 0..60

    float acc[4][4] = {};

    for (int k0 = 0; k0 < K; k0 += BK) {
        // A tile: 64x16, coalesced along K (16 floats per row)
        #pragma unroll
        for (int i = 0; i < 4; i++) {
            int idx = tid + i * 256;
            int r = idx >> 4, c = idx & 15;
            As[c][r] = A[(size_t)(bm + r) * K + k0 + c];
        }
        // B tile: 16x64, coalesced along N
        #pragma unroll
        for (int i = 0; i < 4; i++) {
            int idx = tid + i * 256;
            int r = idx >> 6, c = idx & 63;
            Bs[r][c] = B[(size_t)(k0 + r) * N + bn + c];
        }
        __syncthreads();

        #pragma unroll
        for (int kk = 0; kk < BK; kk++) {
            float a[4], b[4];
            #pragma unroll
            for (int i = 0; i < 4; i++) a[i] = As[kk][tr + i];
            #pragma unroll
            for (int j = 0; j < 4; j++) b[j] = Bs[kk][tc + j];
            #pragma unroll
            for (int i = 0; i < 4; i++)
                #pragma unroll
                for (int j = 0; j < 4; j++)
                    acc[i][j] += a[i] * b[j];
        }
        __syncthreads();
    }

    #pragma unroll
    for (int i = 0; i < 4; i++)
        #pragma unroll
        for (int j = 0; j < 4; j++)
            C[(size_t)(bm + tr + i) * N + bn + tc + j] = acc[i][j] + bias[bn + tc + j];
}

// ---------------- CSR build over dst = adj[0] --------------------------------
__global__ void zero_ints(int* p, int n) {
    int i = blockIdx.x * blockDim.x + threadIdx.x;
    if (i < n) p[i] = 0;
}

__global__ void count_edges(const int* __restrict__ dst, int* __restrict__ counts, int ne) {
    int e = blockIdx.x * blockDim.x + threadIdx.x;
    if (e < ne) atomicAdd(&counts[dst[e]], 1);
}

// one block of 1024 threads scans 4096 counts -> offsets (exclusive), cursor copy
__global__ __launch_bounds__(1024) void scan_offsets(
    const int* __restrict__ counts, int* __restrict__ offsets, int* __restrict__ cursor)
{
    __shared__ int wsum[16];
    const int tid  = threadIdx.x;
    const int lane = tid & 63;
    const int wid  = tid >> 6;

    int c[4];
    int base = tid * 4;
    int s = 0;
    #pragma unroll
    for (int i = 0; i < 4; i++) { c[i] = counts[base + i]; s += c[i]; }

    // inclusive wave scan of s
    int v = s;
    #pragma unroll
    for (int off = 1; off < 64; off <<= 1) {
        int t = __shfl_up(v, off);
        if (lane >= off) v += t;
    }
    if (lane == 63) wsum[wid] = v;
    __syncthreads();
    if (wid == 0) {
        int w = (lane < 16) ? wsum[lane] : 0;
        #pragma unroll
        for (int off = 1; off < 16; off <<= 1) {
            int t = __shfl_up(w, off);
            if (lane >= off) w += t;
        }
        if (lane < 16) wsum[lane] = w;
    }
    __syncthreads();

    int prefix = (wid > 0 ? wsum[wid - 1] : 0) + (v - s);  // exclusive for this thread
    int run = prefix;
    #pragma unroll
    for (int i = 0; i < 4; i++) {
        offsets[base + i] = run;
        cursor[base + i]  = run;
        run += c[i];
    }
    if (tid == 1023) offsets[4096] = run;
}

__global__ void scatter_edges(const int* __restrict__ dst, int* __restrict__ cursor,
                              int* __restrict__ eid, int ne) {
    int e = blockIdx.x * blockDim.x + threadIdx.x;
    if (e < ne) {
        int p = atomicAdd(&cursor[dst[e]], 1);
        eid[p] = e;
    }
}

// ---------------- fused sparse attention ------------------------------------
// One wave per (nh, dst). q-row in registers, online softmax, result overwrites Q.
__global__ __launch_bounds__(256) void sparse_attn(
    float* __restrict__ Q, const float* __restrict__ K, const float* __restrict__ V,
    const int* __restrict__ src, const float* __restrict__ epe,
    const int* __restrict__ offsets, const int* __restrict__ eid)
{
    const int lane = threadIdx.x & 63;
    const int task = blockIdx.x * 4 + (threadIdx.x >> 6);   // 32*4096 tasks
    const int nh  = task >> 12;         // 0..31
    const int dstn = task & 4095;
    const int n = nh >> 3;
    const int h = nh & 7;

    const size_t rowq = ((size_t)(n * LL + dstn) * MDL) + h * EDIM;
    float qv = Q[rowq + lane];

    const int beg = offsets[dstn];
    const int end = offsets[dstn + 1];
    const float* epe_h = epe + (size_t)nh * NE;

    float m = -INFINITY, z = 0.0f, acc = 0.0f;

    for (int i = beg; i < end; i++) {
        const int e = eid[i];
        const int s = src[e];
        const size_t rowk = ((size_t)(n * LL + s) * MDL) + h * EDIM;
        float dot = qv * K[rowk + lane];
        #pragma unroll
        for (int off = 1; off < 64; off <<= 1)
            dot += __shfl_xor(dot, off);
        float score = TEMP * (dot + epe_h[e]);
        float mnew  = fmaxf(m, score);
        float scale = __expf(m - mnew);      // exp(-inf)=0 handles first iter
        float p     = __expf(score - mnew);
        z   = z * scale + p;
        acc = acc * scale + p * V[rowk + lane];
        m = mnew;
    }

    Q[rowq + lane] = (end > beg) ? (acc / z) : 0.0f;
}

// ---------------- launch ------------------------------------------------------
extern "C" void kernel_launch(void* const* d_in, const int* in_sizes, int n_in,
                              void* d_out, int out_size, void* d_ws, size_t ws_size,
                              hipStream_t stream)
{
    const float* queries = (const float*)d_in[0];
    const float* keys    = (const float*)d_in[1];
    const float* values  = (const float*)d_in[2];
    const int*   adj     = (const int*)d_in[3];   // [2][NE]: dst, src
    const float* epe     = (const float*)d_in[4]; // [N][H][NE]
    const float* Wq = (const float*)d_in[5];
    const float* bq = (const float*)d_in[6];
    const float* Wk = (const float*)d_in[7];
    const float* bk = (const float*)d_in[8];
    const float* Wv = (const float*)d_in[9];
    const float* bv = (const float*)d_in[10];
    const float* Wo = (const float*)d_in[11];
    const float* bo = (const float*)d_in[12];
    float* out = (float*)d_out;

    const int* dst = adj;
    const int* src = adj + NE;

    const size_t NLM = (size_t)NB * LL * MDL;    // 8,388,608 floats

    char* w = (char*)d_ws;
    float* Q  = (float*)w; w += NLM * sizeof(float);
    float* Kb = (float*)w; w += NLM * sizeof(float);
    float* Vb = (float*)w; w += NLM * sizeof(float);
    int* counts  = (int*)w; w += 4096 * sizeof(int);
    int* offsets = (int*)w; w += 4100 * sizeof(int);
    int* cursor  = (int*)w; w += 4096 * sizeof(int);
    int* eid     = (int*)w; w += NE * sizeof(int);

    const int M = NB * LL;   // 16384

    // CSR build
    zero_ints<<<16, 256, 0, stream>>>(counts, 4096);
    count_edges<<<NE / 256, 256, 0, stream>>>(dst, counts, NE);
    scan_offsets<<<1, 1024, 0, stream>>>(counts, offsets, cursor);
    scatter_edges<<<NE / 256, 256, 0, stream>>>(dst, cursor, eid, NE);

    // QKV projections
    dim3 g(MDL / BN, M / BM);
    gemm_bias<<<g, 256, 0, stream>>>(queries, Wq, bq, Q,  M, MDL, IN_C);
    gemm_bias<<<g, 256, 0, stream>>>(keys,    Wk, bk, Kb, M, MDL, IN_C);
    gemm_bias<<<g, 256, 0, stream>>>(values,  Wv, bv, Vb, M, MDL, IN_C);

    // fused sparse attention (32*4096 waves, 4 waves/block)
    sparse_attn<<<(32 * 4096) / 4, 256, 0, stream>>>(Q, Kb, Vb, src, epe, offsets, eid);

    // output projection
    gemm_bias<<<g, 256, 0, stream>>>(Q, Wo, bo, out, M, MDL, MDL);
}

// Round 2
// 202.508 us; speedup vs baseline: 3.4202x; 3.4202x over previous
//
#include <hip/hip_runtime.h>
#include <hip/hip_bf16.h>
#include <math.h>
#include <stdint.h>

// Problem constants (SparseAttention_46969762349725)
#define HEADS 8
#define IN_C  256
#define MDL   512
#define NB    4        // batch
#define LL    4096     // nodes
#define NE    65536    // edges
#define EDIM  64       // per-head dim = MDL/HEADS
#define TEMP  0.125f   // 1/sqrt(64)

typedef __bf16 bf16x8 __attribute__((ext_vector_type(8)));
typedef float  f32x4  __attribute__((ext_vector_type(4)));
typedef short  short8 __attribute__((ext_vector_type(8)));

__device__ __forceinline__ void glds16(const void* g, void* l) {
    __builtin_amdgcn_global_load_lds(
        (const __attribute__((address_space(1))) void*)g,
        (__attribute__((address_space(3))) void*)l, 16, 0, 0);
}

// ---------------- fp32 -> bf16 convert (8 elems/thread) ----------------------
__global__ __launch_bounds__(256) void cvt_bf16(
    const float* __restrict__ x, __hip_bfloat16* __restrict__ y, int n8)
{
    int i = blockIdx.x * 256 + threadIdx.x;
    if (i >= n8) return;
    const float4* xv = (const float4*)x;
    float4 a = xv[2 * i], b = xv[2 * i + 1];
    union { short8 v; __hip_bfloat16 h[8]; } u;
    u.h[0] = __float2bfloat16(a.x); u.h[1] = __float2bfloat16(a.y);
    u.h[2] = __float2bfloat16(a.z); u.h[3] = __float2bfloat16(a.w);
    u.h[4] = __float2bfloat16(b.x); u.h[5] = __float2bfloat16(b.y);
    u.h[6] = __float2bfloat16(b.z); u.h[7] = __float2bfloat16(b.w);
    *(short8*)(y + (size_t)i * 8) = u.v;
}

// ---------------- W[K][N] fp32 -> Wt[N][K] bf16 (32x32 LDS transpose) --------
__global__ __launch_bounds__(256) void transpose_bf16(
    const float* __restrict__ W, __hip_bfloat16* __restrict__ Wt, int K, int N)
{
    __shared__ float t[32][33];
    int bx = blockIdx.x * 32;              // n
    int by = blockIdx.y * 32;              // k
    int tx = threadIdx.x & 31, ty = threadIdx.x >> 5;   // 32 x 8
    #pragma unroll
    for (int i = 0; i < 4; i++)
        t[ty + i * 8][tx] = W[(size_t)(by + ty + i * 8) * N + bx + tx];
    __syncthreads();
    #pragma unroll
    for (int i = 0; i < 4; i++)
        Wt[(size_t)(bx + ty + i * 8) * K + by + tx] =
            __float2bfloat16(t[tx][ty + i * 8]);
}

// ---------------- bf16 MFMA GEMM: C = A[MxK] @ Bt[NxK]^T + bias --------------
// 128x128 tile, BK=32, 4 waves (2x2, 64x64 each), 16x16x32 bf16 MFMA.
template<int OUTBF>
__global__ __launch_bounds__(256) void gemm_mfma(
    const __hip_bfloat16* __restrict__ A,   // [M][K] bf16
    const __hip_bfloat16* __restrict__ Bt,  // [N][K] bf16
    const float* __restrict__ bias,
    float* __restrict__ Cf, __hip_bfloat16* __restrict__ Cb,
    int M, int N, int K)
{
    __shared__ __align__(16) __hip_bfloat16 As[128 * 32];
    __shared__ __align__(16) __hip_bfloat16 Bs[128 * 32];

    const int tid  = threadIdx.x;
    const int lane = tid & 63;
    const int w    = tid >> 6;
    const int wr   = w >> 1, wc = w & 1;
    const int bm   = blockIdx.y * 128, bn = blockIdx.x * 128;

    // staging: 16B chunk idx = iter*256 + tid; row = idx>>2, chunk = (idx&3)^(row&3)
    const int r0 = tid >> 2;
    const int c0 = (tid & 3) ^ (r0 & 3);
    const int r1 = (256 + tid) >> 2;
    const int c1 = ((256 + tid) & 3) ^ (r1 & 3);
    const __hip_bfloat16* gA0 = A  + (size_t)(bm + r0) * K + c0 * 8;
    const __hip_bfloat16* gA1 = A  + (size_t)(bm + r1) * K + c1 * 8;
    const __hip_bfloat16* gB0 = Bt + (size_t)(bn + r0) * K + c0 * 8;
    const __hip_bfloat16* gB1 = Bt + (size_t)(bn + r1) * K + c1 * 8;
    __hip_bfloat16* lA0 = As + (size_t)(w * 64) * 8;
    __hip_bfloat16* lA1 = As + (size_t)(256 + w * 64) * 8;
    __hip_bfloat16* lB0 = Bs + (size_t)(w * 64) * 8;
    __hip_bfloat16* lB1 = Bs + (size_t)(256 + w * 64) * 8;

    // fragment LDS element offsets (constant over k-steps)
    int fa[4], fb[4];
    #pragma unroll
    for (int i = 0; i < 4; i++) {
        int rA = wr * 64 + i * 16 + (lane & 15);
        fa[i] = rA * 32 + (((lane >> 4) ^ (rA & 3)) * 8);
        int rB = wc * 64 + i * 16 + (lane & 15);
        fb[i] = rB * 32 + (((lane >> 4) ^ (rB & 3)) * 8);
    }

    f32x4 acc[4][4] = {};

    for (int k0 = 0; k0 < K; k0 += 32) {
        glds16(gA0 + k0, lA0);
        glds16(gA1 + k0, lA1);
        glds16(gB0 + k0, lB0);
        glds16(gB1 + k0, lB1);
        __syncthreads();

        bf16x8 av[4], bv[4];
        #pragma unroll
        for (int i = 0; i < 4; i++) av[i] = *(const bf16x8*)(As + fa[i]);
        #pragma unroll
        for (int i = 0; i < 4; i++) bv[i] = *(const bf16x8*)(Bs + fb[i]);
        #pragma unroll
        for (int mi = 0; mi < 4; mi++)
            #pragma unroll
            for (int ni = 0; ni < 4; ni++)
                acc[mi][ni] = __builtin_amdgcn_mfma_f32_16x16x32_bf16(
                    av[mi], bv[ni], acc[mi][ni], 0, 0, 0);
        __syncthreads();
    }

    #pragma unroll
    for (int mi = 0; mi < 4; mi++) {
        int row = bm + wr * 64 + mi * 16 + (lane >> 4) * 4;
        #pragma unroll
        for (int ni = 0; ni < 4; ni++) {
            int col = bn + wc * 64 + ni * 16 + (lane & 15);
            float bb = bias[col];
            #pragma unroll
            for (int j = 0; j < 4; j++) {
                float vv = acc[mi][ni][j] + bb;
                if (OUTBF) Cb[(size_t)(row + j) * N + col] = __float2bfloat16(vv);
                else       Cf[(size_t)(row + j) * N + col] = vv;
            }
        }
    }
}

// ---------------- CSR build over dst = adj[0] --------------------------------
__global__ void zero_ints(int* p, int n) {
    int i = blockIdx.x * blockDim.x + threadIdx.x;
    if (i < n) p[i] = 0;
}

__global__ void count_edges(const int* __restrict__ dst, int* __restrict__ counts, int ne) {
    int e = blockIdx.x * blockDim.x + threadIdx.x;
    if (e < ne) atomicAdd(&counts[dst[e]], 1);
}

__global__ __launch_bounds__(1024) void scan_offsets(
    const int* __restrict__ counts, int* __restrict__ offsets, int* __restrict__ cursor)
{
    __shared__ int wsum[16];
    const int tid  = threadIdx.x;
    const int lane = tid & 63;
    const int wid  = tid >> 6;

    int c[4];
    int base = tid * 4;
    int s = 0;
    #pragma unroll
    for (int i = 0; i < 4; i++) { c[i] = counts[base + i]; s += c[i]; }

    int v = s;
    #pragma unroll
    for (int off = 1; off < 64; off <<= 1) {
        int t = __shfl_up(v, off);
        if (lane >= off) v += t;
    }
    if (lane == 63) wsum[wid] = v;
    __syncthreads();
    if (wid == 0) {
        int wv = (lane < 16) ? wsum[lane] : 0;
        #pragma unroll
        for (int off = 1; off < 16; off <<= 1) {
            int t = __shfl_up(wv, off);
            if (lane >= off) wv += t;
        }
        if (lane < 16) wsum[lane] = wv;
    }
    __syncthreads();

    int prefix = (wid > 0 ? wsum[wid - 1] : 0) + (v - s);
    int run = prefix;
    #pragma unroll
    for (int i = 0; i < 4; i++) {
        offsets[base + i] = run;
        cursor[base + i]  = run;
        run += c[i];
    }
    if (tid == 1023) offsets[4096] = run;
}

__global__ void scatter_edges(const int* __restrict__ dst, int* __restrict__ cursor,
                              int* __restrict__ eid, int ne) {
    int e = blockIdx.x * blockDim.x + threadIdx.x;
    if (e < ne) {
        int p = atomicAdd(&cursor[dst[e]], 1);
        eid[p] = e;
    }
}

// ---------------- fused sparse attention, all 8 heads per wave ---------------
// wave = one (n, dst) node; 8-lane group per head; lane holds 8 dims (bf16x8).
__global__ __launch_bounds__(256) void sparse_attn2(
    const __hip_bfloat16* __restrict__ Qb, const __hip_bfloat16* __restrict__ Kb,
    const __hip_bfloat16* __restrict__ Vb,
    const int* __restrict__ src, const float* __restrict__ epe,
    const int* __restrict__ offsets, const int* __restrict__ eid,
    __hip_bfloat16* __restrict__ O)
{
    const int lane = threadIdx.x & 63;
    const int task = blockIdx.x * 4 + (threadIdx.x >> 6);   // n*LL + dstn
    const int n    = task >> 12;
    const int dstn = task & 4095;
    const int hg   = lane >> 3;        // head 0..7

    const size_t rowbase = (size_t)task * MDL;
    bf16x8 q8 = *(const bf16x8*)(Qb + rowbase + lane * 8);
    float qf[8];
    #pragma unroll
    for (int j = 0; j < 8; j++) qf[j] = (float)q8[j];

    const int beg = offsets[dstn];
    const int end = offsets[dstn + 1];
    const float* epe_h = epe + (size_t)(n * HEADS + hg) * NE;

    float m = -INFINITY, z = 0.0f;
    float acc[8] = {};

    bf16x8 kc, vc;
    float  pec = 0.0f;
    if (beg < end) {
        int e = eid[beg];
        int s = src[e];
        size_t rk = ((size_t)(n * LL + s)) * MDL + lane * 8;
        kc = *(const bf16x8*)(Kb + rk);
        vc = *(const bf16x8*)(Vb + rk);
        pec = epe_h[e];
    }

    for (int i = beg; i < end; i++) {
        bf16x8 k8 = kc, v8 = vc;
        float pe = pec;
        if (i + 1 < end) {
            int e2 = eid[i + 1];
            int s2 = src[e2];
            size_t rk2 = ((size_t)(n * LL + s2)) * MDL + lane * 8;
            kc = *(const bf16x8*)(Kb + rk2);
            vc = *(const bf16x8*)(Vb + rk2);
            pec = epe_h[e2];
        }

        float dot = 0.0f;
        #pragma unroll
        for (int j = 0; j < 8; j++) dot += qf[j] * (float)k8[j];
        dot += __shfl_xor(dot, 1);
        dot += __shfl_xor(dot, 2);
        dot += __shfl_xor(dot, 4);

        float score = TEMP * (dot + pe);
        float mnew  = fmaxf(m, score);
        float sc    = __expf(m - mnew);       // exp(-inf)=0 covers first iter
        float p     = __expf(score - mnew);
        z = z * sc + p;
        #pragma unroll
        for (int j = 0; j < 8; j++) acc[j] = acc[j] * sc + p * (float)v8[j];
        m = mnew;
    }

    float inv = (end > beg) ? (1.0f / z) : 0.0f;
    union { short8 v; __hip_bfloat16 h[8]; } u;
    #pragma unroll
    for (int j = 0; j < 8; j++) u.h[j] = __float2bfloat16(acc[j] * inv);
    *(short8*)(O + rowbase + lane * 8) = u.v;
}

// ---------------- launch ------------------------------------------------------
extern "C" void kernel_launch(void* const* d_in, const int* in_sizes, int n_in,
                              void* d_out, int out_size, void* d_ws, size_t ws_size,
                              hipStream_t stream)
{
    const float* queries = (const float*)d_in[0];
    const float* keys    = (const float*)d_in[1];
    const float* values  = (const float*)d_in[2];
    const int*   adj     = (const int*)d_in[3];
    const float* epe     = (const float*)d_in[4];
    const float* Wq = (const float*)d_in[5];
    const float* bq = (const float*)d_in[6];
    const float* Wk = (const float*)d_in[7];
    const float* bk = (const float*)d_in[8];
    const float* Wv = (const float*)d_in[9];
    const float* bv = (const float*)d_in[10];
    const float* Wo = (const float*)d_in[11];
    const float* bo = (const float*)d_in[12];
    float* out = (float*)d_out;

    const int* dst = adj;
    const int* src = adj + NE;

    const int    M   = NB * LL;                     // 16384
    const size_t NLM = (size_t)M * MDL;             // 8,388,608
    const size_t NLK = (size_t)M * IN_C;            // 4,194,304

    char* w = (char*)d_ws;
    __hip_bfloat16* Qb  = (__hip_bfloat16*)w; w += NLM * 2;      // 16.78 MB
    __hip_bfloat16* Kb  = (__hip_bfloat16*)w; w += NLM * 2;
    __hip_bfloat16* Vb  = (__hip_bfloat16*)w; w += NLM * 2;
    char* inbf_base = w;
    __hip_bfloat16* Qin = (__hip_bfloat16*)w; w += NLK * 2;      // 8.39 MB
    __hip_bfloat16* Kin = (__hip_bfloat16*)w; w += NLK * 2;
    __hip_bfloat16* Vin = (__hip_bfloat16*)w; w += NLK * 2;
    __hip_bfloat16* Ob  = (__hip_bfloat16*)inbf_base;            // aliases Qin/Kin (16.78 MB)
    __hip_bfloat16* Wqt = (__hip_bfloat16*)w; w += (size_t)MDL * IN_C * 2;
    __hip_bfloat16* Wkt = (__hip_bfloat16*)w; w += (size_t)MDL * IN_C * 2;
    __hip_bfloat16* Wvt = (__hip_bfloat16*)w; w += (size_t)MDL * IN_C * 2;
    __hip_bfloat16* Wot = (__hip_bfloat16*)w; w += (size_t)MDL * MDL * 2;
    int* counts  = (int*)w; w += 4096 * sizeof(int);
    int* offsets = (int*)w; w += 4100 * sizeof(int);
    int* cursor  = (int*)w; w += 4096 * sizeof(int);
    int* eid     = (int*)w; w += NE * sizeof(int);

    // CSR build
    zero_ints<<<16, 256, 0, stream>>>(counts, 4096);
    count_edges<<<NE / 256, 256, 0, stream>>>(dst, counts, NE);
    scan_offsets<<<1, 1024, 0, stream>>>(counts, offsets, cursor);
    scatter_edges<<<NE / 256, 256, 0, stream>>>(dst, cursor, eid, NE);

    // input conversions (fp32 -> bf16)
    const int n8 = (int)(NLK / 8);                  // 524288
    cvt_bf16<<<n8 / 256, 256, 0, stream>>>(queries, Qin, n8);
    cvt_bf16<<<n8 / 256, 256, 0, stream>>>(keys,    Kin, n8);
    cvt_bf16<<<n8 / 256, 256, 0, stream>>>(values,  Vin, n8);

    // weight transpose+convert: W[K][N] -> Wt[N][K] bf16
    transpose_bf16<<<dim3(MDL / 32, IN_C / 32), 256, 0, stream>>>(Wq, Wqt, IN_C, MDL);
    transpose_bf16<<<dim3(MDL / 32, IN_C / 32), 256, 0, stream>>>(Wk, Wkt, IN_C, MDL);
    transpose_bf16<<<dim3(MDL / 32, IN_C / 32), 256, 0, stream>>>(Wv, Wvt, IN_C, MDL);
    transpose_bf16<<<dim3(MDL / 32, MDL / 32), 256, 0, stream>>>(Wo, Wot, MDL, MDL);

    // QKV projections (bf16 out)
    dim3 g(MDL / 128, M / 128);                     // (4, 128)
    gemm_mfma<1><<<g, 256, 0, stream>>>(Qin, Wqt, bq, nullptr, Qb, M, MDL, IN_C);
    gemm_mfma<1><<<g, 256, 0, stream>>>(Kin, Wkt, bk, nullptr, Kb, M, MDL, IN_C);
    gemm_mfma<1><<<g, 256, 0, stream>>>(Vin, Wvt, bv, nullptr, Vb, M, MDL, IN_C);

    // fused sparse attention (16384 node-waves, 4 waves/block)
    sparse_attn2<<<(NB * LL) / 4, 256, 0, stream>>>(Qb, Kb, Vb, src, epe, offsets, eid, Ob);

    // output projection (fp32 out + bias)
    gemm_mfma<0><<<g, 256, 0, stream>>>(Ob, Wot, bo, out, nullptr, M, MDL, MDL);
}

// Round 3
// 155.426 us; speedup vs baseline: 4.4563x; 1.3029x over previous
//
#include <hip/hip_runtime.h>
#include <hip/hip_bf16.h>
#include <math.h>
#include <stdint.h>

// Problem constants (SparseAttention_46969762349725)
#define HEADS 8
#define IN_C  256
#define MDL   512
#define NB    4        // batch
#define LL    4096     // nodes
#define NE    65536    // edges
#define EDIM  64       // per-head dim = MDL/HEADS
#define TEMP  0.125f   // 1/sqrt(64)

typedef __bf16 bf16x8 __attribute__((ext_vector_type(8)));
typedef float  f32x4  __attribute__((ext_vector_type(4)));
typedef short  short8 __attribute__((ext_vector_type(8)));

__device__ __forceinline__ void glds16(const void* g, void* l) {
    __builtin_amdgcn_global_load_lds(
        (const __attribute__((address_space(1))) void*)g,
        (__attribute__((address_space(3))) void*)l, 16, 0, 0);
}

// ---------------- fused fp32 -> bf16 convert, all 3 inputs -------------------
#define N8 524288   // (16384*256)/8 per input
__global__ __launch_bounds__(256) void cvt3_bf16(
    const float* __restrict__ q, const float* __restrict__ k,
    const float* __restrict__ v,
    __hip_bfloat16* __restrict__ Qin, __hip_bfloat16* __restrict__ Kin,
    __hip_bfloat16* __restrict__ Vin)
{
    int i = blockIdx.x * 256 + threadIdx.x;        // 0 .. 3*N8
    int which = i >> 19;                            // /N8
    int j = i & (N8 - 1);
    const float* x = (which == 0) ? q : (which == 1) ? k : v;
    __hip_bfloat16* y = (which == 0) ? Qin : (which == 1) ? Kin : Vin;
    const float4* xv = (const float4*)x;
    float4 a = xv[2 * j], b = xv[2 * j + 1];
    union { short8 v8; __hip_bfloat16 h[8]; } u;
    u.h[0] = __float2bfloat16(a.x); u.h[1] = __float2bfloat16(a.y);
    u.h[2] = __float2bfloat16(a.z); u.h[3] = __float2bfloat16(a.w);
    u.h[4] = __float2bfloat16(b.x); u.h[5] = __float2bfloat16(b.y);
    u.h[6] = __float2bfloat16(b.z); u.h[7] = __float2bfloat16(b.w);
    *(short8*)(y + (size_t)j * 8) = u.v8;
}

// ---------------- all 4 weight transposes in one launch ----------------------
// W[K][N] fp32 -> Wt[N][K] bf16; blocks 0..383 = Wq/Wk/Wv (K=256), 384..639 = Wo
__global__ __launch_bounds__(256) void transpose_all(
    const float* __restrict__ Wq, const float* __restrict__ Wk,
    const float* __restrict__ Wv, const float* __restrict__ Wo,
    __hip_bfloat16* __restrict__ Wqt, __hip_bfloat16* __restrict__ Wkt,
    __hip_bfloat16* __restrict__ Wvt, __hip_bfloat16* __restrict__ Wot)
{
    __shared__ float t[32][33];
    int b = blockIdx.x;
    const float* W; __hip_bfloat16* Wt; int K, tt;
    if (b < 384) {
        int m = b >> 7; tt = b & 127; K = IN_C;
        W  = (m == 0) ? Wq  : (m == 1) ? Wk  : Wv;
        Wt = (m == 0) ? Wqt : (m == 1) ? Wkt : Wvt;
    } else {
        tt = b - 384; K = MDL; W = Wo; Wt = Wot;
    }
    const int N = MDL;
    int bx = (tt & 15) * 32;            // n
    int by = (tt >> 4) * 32;            // k
    int tx = threadIdx.x & 31, ty = threadIdx.x >> 5;   // 32 x 8
    #pragma unroll
    for (int i = 0; i < 4; i++)
        t[ty + i * 8][tx] = W[(size_t)(by + ty + i * 8) * N + bx + tx];
    __syncthreads();
    #pragma unroll
    for (int i = 0; i < 4; i++)
        Wt[(size_t)(bx + ty + i * 8) * K + by + tx] =
            __float2bfloat16(t[tx][ty + i * 8]);
}

// ---------------- bf16 MFMA GEMM body ---------------------------------------
// 128x128 tile, BK=32, 4 waves (2x2, 64x64 each), 16x16x32 bf16 MFMA.
template<int OUTBF>
__device__ __forceinline__ void gemm_body(
    const __hip_bfloat16* __restrict__ A, const __hip_bfloat16* __restrict__ Bt,
    const float* __restrict__ bias, float* __restrict__ Cf,
    __hip_bfloat16* __restrict__ Cb, int M, int N, int K,
    __hip_bfloat16* As, __hip_bfloat16* Bs)
{
    const int tid  = threadIdx.x;
    const int lane = tid & 63;
    const int w    = tid >> 6;
    const int wr   = w >> 1, wc = w & 1;
    const int bm   = blockIdx.y * 128, bn = blockIdx.x * 128;

    const int r0 = tid >> 2;
    const int c0 = (tid & 3) ^ (r0 & 3);
    const int r1 = (256 + tid) >> 2;
    const int c1 = ((256 + tid) & 3) ^ (r1 & 3);
    const __hip_bfloat16* gA0 = A  + (size_t)(bm + r0) * K + c0 * 8;
    const __hip_bfloat16* gA1 = A  + (size_t)(bm + r1) * K + c1 * 8;
    const __hip_bfloat16* gB0 = Bt + (size_t)(bn + r0) * K + c0 * 8;
    const __hip_bfloat16* gB1 = Bt + (size_t)(bn + r1) * K + c1 * 8;
    __hip_bfloat16* lA0 = As + (size_t)(w * 64) * 8;
    __hip_bfloat16* lA1 = As + (size_t)(256 + w * 64) * 8;
    __hip_bfloat16* lB0 = Bs + (size_t)(w * 64) * 8;
    __hip_bfloat16* lB1 = Bs + (size_t)(256 + w * 64) * 8;

    int fa[4], fb[4];
    #pragma unroll
    for (int i = 0; i < 4; i++) {
        int rA = wr * 64 + i * 16 + (lane & 15);
        fa[i] = rA * 32 + (((lane >> 4) ^ (rA & 3)) * 8);
        int rB = wc * 64 + i * 16 + (lane & 15);
        fb[i] = rB * 32 + (((lane >> 4) ^ (rB & 3)) * 8);
    }

    f32x4 acc[4][4] = {};

    for (int k0 = 0; k0 < K; k0 += 32) {
        glds16(gA0 + k0, lA0);
        glds16(gA1 + k0, lA1);
        glds16(gB0 + k0, lB0);
        glds16(gB1 + k0, lB1);
        __syncthreads();

        bf16x8 av[4], bv[4];
        #pragma unroll
        for (int i = 0; i < 4; i++) av[i] = *(const bf16x8*)(As + fa[i]);
        #pragma unroll
        for (int i = 0; i < 4; i++) bv[i] = *(const bf16x8*)(Bs + fb[i]);
        #pragma unroll
        for (int mi = 0; mi < 4; mi++)
            #pragma unroll
            for (int ni = 0; ni < 4; ni++)
                acc[mi][ni] = __builtin_amdgcn_mfma_f32_16x16x32_bf16(
                    av[mi], bv[ni], acc[mi][ni], 0, 0, 0);
        __syncthreads();
    }

    #pragma unroll
    for (int mi = 0; mi < 4; mi++) {
        int row = bm + wr * 64 + mi * 16 + (lane >> 4) * 4;
        #pragma unroll
        for (int ni = 0; ni < 4; ni++) {
            int col = bn + wc * 64 + ni * 16 + (lane & 15);
            float bb = bias[col];
            #pragma unroll
            for (int j = 0; j < 4; j++) {
                float vv = acc[mi][ni][j] + bb;
                if (OUTBF) Cb[(size_t)(row + j) * N + col] = __float2bfloat16(vv);
                else       Cf[(size_t)(row + j) * N + col] = vv;
            }
        }
    }
}

// QKV: one launch, gridDim.z = 3 selects the matrix
__global__ __launch_bounds__(256) void gemm_qkv(
    const __hip_bfloat16* __restrict__ A0, const __hip_bfloat16* __restrict__ A1,
    const __hip_bfloat16* __restrict__ A2,
    const __hip_bfloat16* __restrict__ B0, const __hip_bfloat16* __restrict__ B1,
    const __hip_bfloat16* __restrict__ B2,
    const float* __restrict__ b0, const float* __restrict__ b1,
    const float* __restrict__ b2,
    __hip_bfloat16* __restrict__ C0, __hip_bfloat16* __restrict__ C1,
    __hip_bfloat16* __restrict__ C2, int M, int N, int K)
{
    __shared__ __align__(16) __hip_bfloat16 As[128 * 32];
    __shared__ __align__(16) __hip_bfloat16 Bs[128 * 32];
    int z = blockIdx.z;
    const __hip_bfloat16* A  = (z == 0) ? A0 : (z == 1) ? A1 : A2;
    const __hip_bfloat16* Bt = (z == 0) ? B0 : (z == 1) ? B1 : B2;
    const float* bias        = (z == 0) ? b0 : (z == 1) ? b1 : b2;
    __hip_bfloat16* C        = (z == 0) ? C0 : (z == 1) ? C1 : C2;
    gemm_body<1>(A, Bt, bias, nullptr, C, M, N, K, As, Bs);
}

__global__ __launch_bounds__(256) void gemm_out(
    const __hip_bfloat16* __restrict__ A, const __hip_bfloat16* __restrict__ Bt,
    const float* __restrict__ bias, float* __restrict__ C, int M, int N, int K)
{
    __shared__ __align__(16) __hip_bfloat16 As[128 * 32];
    __shared__ __align__(16) __hip_bfloat16 Bs[128 * 32];
    gemm_body<0>(A, Bt, bias, C, nullptr, M, N, K, As, Bs);
}

// ---------------- CSR build over dst = adj[0] --------------------------------
__global__ void zero_ints(int* p, int n) {
    int i = blockIdx.x * blockDim.x + threadIdx.x;
    if (i < n) p[i] = 0;
}

__global__ void count_edges(const int* __restrict__ dst, int* __restrict__ counts, int ne) {
    int e = blockIdx.x * blockDim.x + threadIdx.x;
    if (e < ne) atomicAdd(&counts[dst[e]], 1);
}

__global__ __launch_bounds__(1024) void scan_offsets(
    const int* __restrict__ counts, int* __restrict__ offsets, int* __restrict__ cursor)
{
    __shared__ int wsum[16];
    const int tid  = threadIdx.x;
    const int lane = tid & 63;
    const int wid  = tid >> 6;

    int c[4];
    int base = tid * 4;
    int s = 0;
    #pragma unroll
    for (int i = 0; i < 4; i++) { c[i] = counts[base + i]; s += c[i]; }

    int v = s;
    #pragma unroll
    for (int off = 1; off < 64; off <<= 1) {
        int t = __shfl_up(v, off);
        if (lane >= off) v += t;
    }
    if (lane == 63) wsum[wid] = v;
    __syncthreads();
    if (wid == 0) {
        int wv = (lane < 16) ? wsum[lane] : 0;
        #pragma unroll
        for (int off = 1; off < 16; off <<= 1) {
            int t = __shfl_up(wv, off);
            if (lane >= off) wv += t;
        }
        if (lane < 16) wsum[lane] = wv;
    }
    __syncthreads();

    int prefix = (wid > 0 ? wsum[wid - 1] : 0) + (v - s);
    int run = prefix;
    #pragma unroll
    for (int i = 0; i < 4; i++) {
        offsets[base + i] = run;
        cursor[base + i]  = run;
        run += c[i];
    }
    if (tid == 1023) offsets[4096] = run;
}

// scatter edges into CSR slots; also gather src and epe into CSR order.
// epe_s layout: [n][pos][8 heads] (32B per (n,pos))
__global__ void scatter_edges2(
    const int* __restrict__ dst, const int* __restrict__ srcarr,
    const float* __restrict__ epe, int* __restrict__ cursor,
    int* __restrict__ src_s, float* __restrict__ epe_s, int ne)
{
    int e = blockIdx.x * blockDim.x + threadIdx.x;
    if (e >= ne) return;
    int p = atomicAdd(&cursor[dst[e]], 1);
    src_s[p] = srcarr[e];
    #pragma unroll
    for (int n = 0; n < NB; n++) {
        float4 a, b;
        const float* base = epe + (size_t)(n * HEADS) * NE + e;
        a.x = base[0 * NE]; a.y = base[1 * NE]; a.z = base[2 * NE]; a.w = base[3 * NE];
        b.x = base[4 * NE]; b.y = base[5 * NE]; b.z = base[6 * NE]; b.w = base[7 * NE];
        float* o = epe_s + ((size_t)n * NE + p) * 8;
        *(float4*)o       = a;
        *(float4*)(o + 4) = b;
    }
}

// ---------------- fused sparse attention, 4-edge batches ---------------------
// wave = one (n, dst) node; 8-lane group per head; lane holds 8 dims (bf16x8).
__global__ __launch_bounds__(128, 4) void sparse_attn3(
    const __hip_bfloat16* __restrict__ Qb, const __hip_bfloat16* __restrict__ Kb,
    const __hip_bfloat16* __restrict__ Vb,
    const int* __restrict__ src_s, const float* __restrict__ epe_s,
    const int* __restrict__ offsets, __hip_bfloat16* __restrict__ O)
{
    const int lane = threadIdx.x & 63;
    const int task = blockIdx.x * 2 + (threadIdx.x >> 6);   // n*LL + dstn
    const int n    = task >> 12;
    const int dstn = task & 4095;
    const int hg   = lane >> 3;        // head 0..7

    const size_t rowbase = (size_t)task * MDL;
    const int beg = offsets[dstn];
    const int end = offsets[dstn + 1];

    union { short8 v8; __hip_bfloat16 h[8]; } uo;
    if (beg == end) {
        #pragma unroll
        for (int j = 0; j < 8; j++) uo.h[j] = __float2bfloat16(0.0f);
        *(short8*)(O + rowbase + lane * 8) = uo.v8;
        return;
    }

    bf16x8 q8 = *(const bf16x8*)(Qb + rowbase + lane * 8);
    float qf[8];
    #pragma unroll
    for (int j = 0; j < 8; j++) qf[j] = (float)q8[j];

    const __hip_bfloat16* Kn = Kb + (size_t)n * LL * MDL + lane * 8;
    const __hip_bfloat16* Vn = Vb + (size_t)n * LL * MDL + lane * 8;
    const float* pe_n = epe_s + (size_t)n * NE * 8 + hg;

    float m = -INFINITY, z = 0.0f;
    float acc[8] = {};

    bf16x8 ka[4], va[4]; float pa[4];
    // load batch at base i (masked with pe=-inf beyond end)
    #define LOADB(i, kk, vv, pp)                                            \
        _Pragma("unroll")                                                   \
        for (int j = 0; j < 4; j++) {                                       \
            int idx = (i) + j;                                              \
            int ok  = idx < end;                                            \
            int s   = ok ? src_s[idx] : 0;                                  \
            size_t rk = (size_t)s * MDL;                                    \
            kk[j] = *(const bf16x8*)(Kn + rk);                              \
            vv[j] = *(const bf16x8*)(Vn + rk);                              \
            pp[j] = ok ? pe_n[(size_t)idx * 8] : -INFINITY;                 \
        }

    LOADB(beg, ka, va, pa)

    for (int i = beg; i < end; i += 4) {
        bf16x8 kb[4], vb[4]; float pb[4];
        if (i + 4 < end) { LOADB(i + 4, kb, vb, pb) }

        float sc4[4];
        #pragma unroll
        for (int j = 0; j < 4; j++) {
            float d = 0.0f;
            #pragma unroll
            for (int dd = 0; dd < 8; dd++) d += qf[dd] * (float)ka[j][dd];
            d += __shfl_xor(d, 1);
            d += __shfl_xor(d, 2);
            d += __shfl_xor(d, 4);
            sc4[j] = TEMP * (d + pa[j]);
        }

        float mb   = fmaxf(fmaxf(sc4[0], sc4[1]), fmaxf(sc4[2], sc4[3]));
        float mnew = fmaxf(m, mb);
        float sc   = __expf(m - mnew);          // exp(-inf)=0 covers first batch
        float p0 = __expf(sc4[0] - mnew);
        float p1 = __expf(sc4[1] - mnew);
        float p2 = __expf(sc4[2] - mnew);
        float p3 = __expf(sc4[3] - mnew);
        z = z * sc + (p0 + p1 + p2 + p3);
        #pragma unroll
        for (int dd = 0; dd < 8; dd++) {
            float t = acc[dd] * sc;
            t = fmaf(p0, (float)va[0][dd], t);
            t = fmaf(p1, (float)va[1][dd], t);
            t = fmaf(p2, (float)va[2][dd], t);
            t = fmaf(p3, (float)va[3][dd], t);
            acc[dd] = t;
        }
        m = mnew;

        #pragma unroll
        for (int j = 0; j < 4; j++) { ka[j] = kb[j]; va[j] = vb[j]; pa[j] = pb[j]; }
    }

    float inv = 1.0f / z;
    #pragma unroll
    for (int j = 0; j < 8; j++) uo.h[j] = __float2bfloat16(acc[j] * inv);
    *(short8*)(O + rowbase + lane * 8) = uo.v8;
    #undef LOADB
}

// ---------------- launch ------------------------------------------------------
extern "C" void kernel_launch(void* const* d_in, const int* in_sizes, int n_in,
                              void* d_out, int out_size, void* d_ws, size_t ws_size,
                              hipStream_t stream)
{
    const float* queries = (const float*)d_in[0];
    const float* keys    = (const float*)d_in[1];
    const float* values  = (const float*)d_in[2];
    const int*   adj     = (const int*)d_in[3];
    const float* epe     = (const float*)d_in[4];
    const float* Wq = (const float*)d_in[5];
    const float* bq = (const float*)d_in[6];
    const float* Wk = (const float*)d_in[7];
    const float* bk = (const float*)d_in[8];
    const float* Wv = (const float*)d_in[9];
    const float* bv = (const float*)d_in[10];
    const float* Wo = (const float*)d_in[11];
    const float* bo = (const float*)d_in[12];
    float* out = (float*)d_out;

    const int* dst = adj;
    const int* src = adj + NE;

    const int    M   = NB * LL;                     // 16384
    const size_t NLM = (size_t)M * MDL;             // 8,388,608
    const size_t NLK = (size_t)M * IN_C;            // 4,194,304

    char* w = (char*)d_ws;
    __hip_bfloat16* Qb  = (__hip_bfloat16*)w; w += NLM * 2;      // 16.78 MB
    __hip_bfloat16* Kb  = (__hip_bfloat16*)w; w += NLM * 2;
    __hip_bfloat16* Vb  = (__hip_bfloat16*)w; w += NLM * 2;
    char* inbf_base = w;
    __hip_bfloat16* Qin = (__hip_bfloat16*)w; w += NLK * 2;      // 8.39 MB
    __hip_bfloat16* Kin = (__hip_bfloat16*)w; w += NLK * 2;
    __hip_bfloat16* Vin = (__hip_bfloat16*)w; w += NLK * 2;
    __hip_bfloat16* Ob  = (__hip_bfloat16*)inbf_base;            // aliases Qin/Kin
    __hip_bfloat16* Wqt = (__hip_bfloat16*)w; w += (size_t)MDL * IN_C * 2;
    __hip_bfloat16* Wkt = (__hip_bfloat16*)w; w += (size_t)MDL * IN_C * 2;
    __hip_bfloat16* Wvt = (__hip_bfloat16*)w; w += (size_t)MDL * IN_C * 2;
    __hip_bfloat16* Wot = (__hip_bfloat16*)w; w += (size_t)MDL * MDL * 2;
    int* counts  = (int*)w; w += 4096 * sizeof(int);
    int* offsets = (int*)w; w += 4100 * sizeof(int);
    int* cursor  = (int*)w; w += 4096 * sizeof(int);
    int*   src_s = (int*)w; w += NE * sizeof(int);
    float* epe_s = (float*)w; w += (size_t)NB * NE * 8 * sizeof(float);  // 8.39 MB

    // CSR build + CSR-order gathers
    zero_ints<<<16, 256, 0, stream>>>(counts, 4096);
    count_edges<<<NE / 256, 256, 0, stream>>>(dst, counts, NE);
    scan_offsets<<<1, 1024, 0, stream>>>(counts, offsets, cursor);
    scatter_edges2<<<NE / 256, 256, 0, stream>>>(dst, src, epe, cursor, src_s, epe_s, NE);

    // input conversions (fp32 -> bf16), one launch
    cvt3_bf16<<<(3 * N8) / 256, 256, 0, stream>>>(queries, keys, values, Qin, Kin, Vin);

    // weight transpose+convert, one launch
    transpose_all<<<640, 256, 0, stream>>>(Wq, Wk, Wv, Wo, Wqt, Wkt, Wvt, Wot);

    // QKV projections (one launch, z=3)
    dim3 g3(MDL / 128, M / 128, 3);
    gemm_qkv<<<g3, 256, 0, stream>>>(Qin, Kin, Vin, Wqt, Wkt, Wvt, bq, bk, bv,
                                     Qb, Kb, Vb, M, MDL, IN_C);

    // fused sparse attention (16384 node-waves, 2 waves/block)
    sparse_attn3<<<(NB * LL) / 2, 128, 0, stream>>>(Qb, Kb, Vb, src_s, epe_s, offsets, Ob);

    // output projection (fp32 out + bias)
    dim3 g(MDL / 128, M / 128);
    gemm_out<<<g, 256, 0, stream>>>(Ob, Wot, bo, out, M, MDL, MDL);
}